// Round 1
// baseline (74.756 us; speedup 1.0000x reference)
//
#include <hip/hip_runtime.h>

#define S_DIM  2048
#define B_DIM  1024
#define SC_DIM 4096

#define BM 128
#define BN 128
#define BK 64
#define LDK 72   // padded k-stride (ushorts): 144B rows -> 2-way bank aliasing (free)

typedef __bf16 bf16x8 __attribute__((ext_vector_type(8)));
typedef float  f32x4  __attribute__((ext_vector_type(4)));
typedef unsigned short u16x4 __attribute__((ext_vector_type(4)));
typedef unsigned short u16x8 __attribute__((ext_vector_type(8)));

__device__ __forceinline__ unsigned short f2bf(float f) {
    unsigned int u = __builtin_bit_cast(unsigned int, f);
    return (unsigned short)((u + 0x7FFFu + ((u >> 16) & 1u)) >> 16);
}

__global__ __launch_bounds__(256, 2)
void opt_gemm_fused(const float* __restrict__ proba,
                    const float* __restrict__ cur,
                    const float* __restrict__ bsc,
                    const float* __restrict__ avail,
                    const float* __restrict__ alloc,
                    float* __restrict__ out)
{
    __shared__ __align__(16) unsigned short sA[BM * LDK];
    __shared__ __align__(16) unsigned short sB[BN * LDK];

    const int tid  = threadIdx.x;
    const int lane = tid & 63;
    const int wid  = tid >> 6;
    const int wm   = wid >> 1;       // 0..1 : wave row
    const int wn   = wid & 1;        // 0..1 : wave col

    const int bm0 = blockIdx.y * BM;
    const int bn0 = blockIdx.x * BN;

    // A staging map: thread -> (float4 idx along k, starting row)
    const int af4 = tid & 15;        // 16 float4 per 64-wide k row
    const int ar0 = tid >> 4;        // 16 rows per pass, 8 passes

    // B staging map: thread -> one n column, half the k range
    const int bnn = tid & 127;       // n within tile
    const int bkh = tid >> 7;        // 0/1 -> k half (32 each)

    const int l16 = lane & 15;
    const int lg  = lane >> 4;

    f32x4 acc[4][4];
    #pragma unroll
    for (int i = 0; i < 4; ++i)
        #pragma unroll
        for (int j = 0; j < 4; ++j)
            acc[i][j] = {0.f, 0.f, 0.f, 0.f};

    for (int k0 = 0; k0 < B_DIM; k0 += BK) {
        // ---- stage A: bf16(proba * cm) -> sA[row][k] ----
        f32x4 av = *(const f32x4*)&avail[k0 + af4 * 4];
        f32x4 al = *(const f32x4*)&alloc[k0 + af4 * 4];
        #pragma unroll
        for (int pass = 0; pass < 8; ++pass) {
            int r = ar0 + pass * 16;
            f32x4 p = *(const f32x4*)&proba[(size_t)(bm0 + r) * B_DIM + k0 + af4 * 4];
            u16x4 w;
            #pragma unroll
            for (int i = 0; i < 4; ++i) {
                float pv = p[i];
                bool oa = (av[i] - pv < 0.f) && (pv > 0.f);
                bool ob = (al[i] + pv < 0.f) && (pv < 0.f);
                float cm = (oa || ob) ? 0.01f : 1.0f;
                w[i] = f2bf(pv * cm);
            }
            *(u16x4*)&sA[r * LDK + af4 * 4] = w;
        }
        // ---- stage B transposed: sB[n][k] = bf16(bsc[k][n]) ----
        #pragma unroll
        for (int g = 0; g < 4; ++g) {
            u16x8 w;
            #pragma unroll
            for (int i = 0; i < 8; ++i) {
                int kk = bkh * 32 + g * 8 + i;
                w[i] = f2bf(bsc[(size_t)(k0 + kk) * SC_DIM + bn0 + bnn]);
            }
            *(u16x8*)&sB[bnn * LDK + bkh * 32 + g * 8] = w;
        }
        __syncthreads();

        // ---- MFMA: 2 k-slices of 32, 4x4 fragments per wave ----
        #pragma unroll
        for (int kk = 0; kk < 2; ++kk) {
            bf16x8 afr[4], bfr[4];
            #pragma unroll
            for (int mf = 0; mf < 4; ++mf)
                afr[mf] = *(const bf16x8*)&sA[(wm * 64 + mf * 16 + l16) * LDK + kk * 32 + lg * 8];
            #pragma unroll
            for (int nf = 0; nf < 4; ++nf)
                bfr[nf] = *(const bf16x8*)&sB[(wn * 64 + nf * 16 + l16) * LDK + kk * 32 + lg * 8];
            #pragma unroll
            for (int mf = 0; mf < 4; ++mf)
                #pragma unroll
                for (int nf = 0; nf < 4; ++nf)
                    acc[mf][nf] = __builtin_amdgcn_mfma_f32_16x16x32_bf16(
                        afr[mf], bfr[nf], acc[mf][nf], 0, 0, 0);
        }
        __syncthreads();
    }

    // ---- epilogue: out = cur + acc ----
    #pragma unroll
    for (int mf = 0; mf < 4; ++mf) {
        #pragma unroll
        for (int j = 0; j < 4; ++j) {
            int row = bm0 + wm * 64 + mf * 16 + lg * 4 + j;
            #pragma unroll
            for (int nf = 0; nf < 4; ++nf) {
                int col = bn0 + wn * 64 + nf * 16 + l16;
                size_t idx = (size_t)row * SC_DIM + col;
                out[idx] = cur[idx] + acc[mf][nf][j];
            }
        }
    }
}

extern "C" void kernel_launch(void* const* d_in, const int* in_sizes, int n_in,
                              void* d_out, int out_size, void* d_ws, size_t ws_size,
                              hipStream_t stream) {
    const float* proba = (const float*)d_in[0];
    const float* cur   = (const float*)d_in[1];
    const float* bsc   = (const float*)d_in[2];
    const float* avail = (const float*)d_in[3];
    const float* alloc = (const float*)d_in[4];
    float* out = (float*)d_out;

    dim3 grid(SC_DIM / BN, S_DIM / BM);   // 32 x 16 = 512 blocks
    opt_gemm_fused<<<grid, 256, 0, stream>>>(proba, cur, bsc, avail, alloc, out);
}

// Round 2
// 44.172 us; speedup vs baseline: 1.6924x; 1.6924x over previous
//
#include <hip/hip_runtime.h>

#define S_DIM  2048
#define B_DIM  1024
#define SC_DIM 4096

#define BM 128
#define BN 128
#define BK 64

typedef __bf16 bf16x8 __attribute__((ext_vector_type(8)));
typedef float  f32x4  __attribute__((ext_vector_type(4)));
typedef unsigned short u16x4 __attribute__((ext_vector_type(4)));
typedef unsigned short u16x8 __attribute__((ext_vector_type(8)));

__device__ __forceinline__ unsigned short f2bf(float f) {
    unsigned int u = __builtin_bit_cast(unsigned int, f);
    return (unsigned short)((u + 0x7FFFu + ((u >> 16) & 1u)) >> 16);
}

__device__ __forceinline__ void gld_lds16(const void* g, void* l) {
    __builtin_amdgcn_global_load_lds(
        (const __attribute__((address_space(1))) unsigned int*)g,
        (__attribute__((address_space(3))) unsigned int*)l, 16, 0, 0);
}

// ---------------- prepack A: wsA[n][k] = bf16(proba*cm), 16B-chunk-swizzled ----------------
// chunk (n,G): data stored at column-chunk (G&~7) | ((G&7)^(n&7))
__global__ __launch_bounds__(256)
void prepack_a(const float* __restrict__ proba,
               const float* __restrict__ avail,
               const float* __restrict__ alloc,
               unsigned short* __restrict__ wsA)
{
    int c = blockIdx.x * 256 + threadIdx.x;      // 0 .. 262143
    int n = c >> 7;                              // row (shop-major index s*B layout -> row n, k = bundle)
    int G = c & 127;                             // 16B chunk within row (8 k each)
    int k = G * 8;

    f32x4 p0 = *(const f32x4*)&proba[(size_t)n * B_DIM + k];
    f32x4 p1 = *(const f32x4*)&proba[(size_t)n * B_DIM + k + 4];
    f32x4 av0 = *(const f32x4*)&avail[k];
    f32x4 av1 = *(const f32x4*)&avail[k + 4];
    f32x4 al0 = *(const f32x4*)&alloc[k];
    f32x4 al1 = *(const f32x4*)&alloc[k + 4];

    u16x8 w;
    #pragma unroll
    for (int i = 0; i < 4; ++i) {
        float pv = p0[i];
        bool oa = (av0[i] - pv < 0.f) && (pv > 0.f);
        bool ob = (al0[i] + pv < 0.f) && (pv < 0.f);
        w[i] = f2bf(pv * ((oa || ob) ? 0.01f : 1.0f));
    }
    #pragma unroll
    for (int i = 0; i < 4; ++i) {
        float pv = p1[i];
        bool oa = (av1[i] - pv < 0.f) && (pv > 0.f);
        bool ob = (al1[i] + pv < 0.f) && (pv < 0.f);
        w[4 + i] = f2bf(pv * ((oa || ob) ? 0.01f : 1.0f));
    }
    int Gs = (G & ~7) | ((G & 7) ^ (n & 7));
    *(u16x8*)&wsA[(size_t)n * B_DIM + Gs * 8] = w;
}

// ---------------- prepack B: wsB[n][k] = bf16(bsc[k][n]) transposed via LDS, swizzled ----------------
__global__ __launch_bounds__(256)
void prepack_b(const float* __restrict__ bsc,
               unsigned short* __restrict__ wsB)
{
    __shared__ float lds[64][129];               // pad 129 -> conflict-free transposed reads
    const int t = threadIdx.x;
    const int bn0 = blockIdx.x * 128;
    const int k0  = blockIdx.y * 64;

    // load 64k x 128n tile, coalesced f32x4
    #pragma unroll
    for (int p = 0; p < 8; ++p) {
        int kl = (t >> 5) + p * 8;
        int cl = (t & 31) * 4;
        f32x4 v = *(const f32x4*)&bsc[(size_t)(k0 + kl) * SC_DIM + bn0 + cl];
        lds[kl][cl]     = v[0];
        lds[kl][cl + 1] = v[1];
        lds[kl][cl + 2] = v[2];
        lds[kl][cl + 3] = v[3];
    }
    __syncthreads();

    // store transposed: thread -> (n, g), 8 k-consecutive elems
    #pragma unroll
    for (int p = 0; p < 4; ++p) {
        int g = t & 7;
        int n = (t >> 3) + p * 32;
        u16x8 w;
        #pragma unroll
        for (int i = 0; i < 8; ++i)
            w[i] = f2bf(lds[g * 8 + i][n]);
        int gs = g ^ (n & 7);
        *(u16x8*)&wsB[(size_t)(bn0 + n) * B_DIM + k0 + gs * 8] = w;
    }
}

// ---------------- main GEMM: out = cur + A_bf16 @ B_bf16^T(packed) ----------------
__global__ __launch_bounds__(256, 2)
void gemm_pk(const unsigned short* __restrict__ wsA,
             const unsigned short* __restrict__ wsB,
             const float* __restrict__ cur,
             float* __restrict__ out)
{
    __shared__ __align__(16) unsigned short sA[BM * BK];   // 16KB, linear (pre-swizzled in ws)
    __shared__ __align__(16) unsigned short sB[BN * BK];   // 16KB

    const int tid  = threadIdx.x;
    const int lane = tid & 63;
    const int wid  = tid >> 6;
    const int wm   = wid >> 1;
    const int wn   = wid & 1;
    const int l16  = lane & 15;
    const int lg   = lane >> 4;

    const int bm0 = blockIdx.y * BM;
    const int bn0 = blockIdx.x * BN;

    f32x4 acc[4][4];
    #pragma unroll
    for (int i = 0; i < 4; ++i)
        #pragma unroll
        for (int j = 0; j < 4; ++j)
            acc[i][j] = {0.f, 0.f, 0.f, 0.f};

    const int cn = tid >> 3;      // staging: row within tile
    const int cg = tid & 7;       // 16B chunk within row

    for (int k0 = 0; k0 < B_DIM; k0 += BK) {
        #pragma unroll
        for (int is = 0; is < 4; ++is) {
            int n = cn + is * 32;
            gld_lds16(wsA + (size_t)(bm0 + n) * B_DIM + k0 + cg * 8,
                      &sA[(is * 256 + tid) * 8]);
        }
        #pragma unroll
        for (int is = 0; is < 4; ++is) {
            int n = cn + is * 32;
            gld_lds16(wsB + (size_t)(bn0 + n) * B_DIM + k0 + cg * 8,
                      &sB[(is * 256 + tid) * 8]);
        }
        __syncthreads();

        #pragma unroll
        for (int kk = 0; kk < 2; ++kk) {
            bf16x8 afr[4], bfr[4];
            #pragma unroll
            for (int mf = 0; mf < 4; ++mf) {
                int r = wm * 64 + mf * 16 + l16;
                afr[mf] = *(const bf16x8*)&sA[r * BK + (((kk * 4 + lg) ^ (r & 7)) * 8)];
            }
            #pragma unroll
            for (int nf = 0; nf < 4; ++nf) {
                int r = wn * 64 + nf * 16 + l16;
                bfr[nf] = *(const bf16x8*)&sB[r * BK + (((kk * 4 + lg) ^ (r & 7)) * 8)];
            }
            #pragma unroll
            for (int mf = 0; mf < 4; ++mf)
                #pragma unroll
                for (int nf = 0; nf < 4; ++nf)
                    acc[mf][nf] = __builtin_amdgcn_mfma_f32_16x16x32_bf16(
                        afr[mf], bfr[nf], acc[mf][nf], 0, 0, 0);
        }
        __syncthreads();
    }

    #pragma unroll
    for (int mf = 0; mf < 4; ++mf) {
        #pragma unroll
        for (int j = 0; j < 4; ++j) {
            int row = bm0 + wm * 64 + mf * 16 + lg * 4 + j;
            #pragma unroll
            for (int nf = 0; nf < 4; ++nf) {
                int col = bn0 + wn * 64 + nf * 16 + l16;
                size_t idx = (size_t)row * SC_DIM + col;
                out[idx] = cur[idx] + acc[mf][nf][j];
            }
        }
    }
}

// ---------------- fallback (R1 kernel, used only if ws too small) ----------------
#define LDK 72
__global__ __launch_bounds__(256, 2)
void opt_gemm_fused(const float* __restrict__ proba,
                    const float* __restrict__ cur,
                    const float* __restrict__ bsc,
                    const float* __restrict__ avail,
                    const float* __restrict__ alloc,
                    float* __restrict__ out)
{
    __shared__ __align__(16) unsigned short sA[BM * LDK];
    __shared__ __align__(16) unsigned short sB[BN * LDK];
    const int tid = threadIdx.x;
    const int lane = tid & 63;
    const int wid = tid >> 6;
    const int wm = wid >> 1, wn = wid & 1;
    const int bm0 = blockIdx.y * BM, bn0 = blockIdx.x * BN;
    const int af4 = tid & 15, ar0 = tid >> 4;
    const int bnn = tid & 127, bkh = tid >> 7;
    const int l16 = lane & 15, lg = lane >> 4;

    f32x4 acc[4][4];
    #pragma unroll
    for (int i = 0; i < 4; ++i)
        #pragma unroll
        for (int j = 0; j < 4; ++j) acc[i][j] = {0.f, 0.f, 0.f, 0.f};

    for (int k0 = 0; k0 < B_DIM; k0 += BK) {
        f32x4 av = *(const f32x4*)&avail[k0 + af4 * 4];
        f32x4 al = *(const f32x4*)&alloc[k0 + af4 * 4];
        #pragma unroll
        for (int pass = 0; pass < 8; ++pass) {
            int r = ar0 + pass * 16;
            f32x4 p = *(const f32x4*)&proba[(size_t)(bm0 + r) * B_DIM + k0 + af4 * 4];
            u16x4 w;
            #pragma unroll
            for (int i = 0; i < 4; ++i) {
                float pv = p[i];
                bool oa = (av[i] - pv < 0.f) && (pv > 0.f);
                bool ob = (al[i] + pv < 0.f) && (pv < 0.f);
                w[i] = f2bf(pv * ((oa || ob) ? 0.01f : 1.0f));
            }
            *(u16x4*)&sA[r * LDK + af4 * 4] = w;
        }
        #pragma unroll
        for (int g = 0; g < 4; ++g) {
            u16x8 w;
            #pragma unroll
            for (int i = 0; i < 8; ++i) {
                int kk = bkh * 32 + g * 8 + i;
                w[i] = f2bf(bsc[(size_t)(k0 + kk) * SC_DIM + bn0 + bnn]);
            }
            *(u16x8*)&sB[bnn * LDK + bkh * 32 + g * 8] = w;
        }
        __syncthreads();
        #pragma unroll
        for (int kk = 0; kk < 2; ++kk) {
            bf16x8 afr[4], bfr[4];
            #pragma unroll
            for (int mf = 0; mf < 4; ++mf)
                afr[mf] = *(const bf16x8*)&sA[(wm * 64 + mf * 16 + l16) * LDK + kk * 32 + lg * 8];
            #pragma unroll
            for (int nf = 0; nf < 4; ++nf)
                bfr[nf] = *(const bf16x8*)&sB[(wn * 64 + nf * 16 + l16) * LDK + kk * 32 + lg * 8];
            #pragma unroll
            for (int mf = 0; mf < 4; ++mf)
                #pragma unroll
                for (int nf = 0; nf < 4; ++nf)
                    acc[mf][nf] = __builtin_amdgcn_mfma_f32_16x16x32_bf16(
                        afr[mf], bfr[nf], acc[mf][nf], 0, 0, 0);
        }
        __syncthreads();
    }
    #pragma unroll
    for (int mf = 0; mf < 4; ++mf)
        #pragma unroll
        for (int j = 0; j < 4; ++j) {
            int row = bm0 + wm * 64 + mf * 16 + lg * 4 + j;
            #pragma unroll
            for (int nf = 0; nf < 4; ++nf) {
                int col = bn0 + wn * 64 + nf * 16 + l16;
                size_t idx = (size_t)row * SC_DIM + col;
                out[idx] = cur[idx] + acc[mf][nf][j];
            }
        }
}

extern "C" void kernel_launch(void* const* d_in, const int* in_sizes, int n_in,
                              void* d_out, int out_size, void* d_ws, size_t ws_size,
                              hipStream_t stream) {
    const float* proba = (const float*)d_in[0];
    const float* cur   = (const float*)d_in[1];
    const float* bsc   = (const float*)d_in[2];
    const float* avail = (const float*)d_in[3];
    const float* alloc = (const float*)d_in[4];
    float* out = (float*)d_out;

    const size_t wsA_bytes = (size_t)S_DIM * B_DIM * 2;   // 4 MB
    const size_t wsB_bytes = (size_t)SC_DIM * B_DIM * 2;  // 8 MB

    if (ws_size >= wsA_bytes + wsB_bytes) {
        unsigned short* wsA = (unsigned short*)d_ws;
        unsigned short* wsB = (unsigned short*)((char*)d_ws + wsA_bytes);

        prepack_a<<<dim3(S_DIM * B_DIM / 8 / 256), 256, 0, stream>>>(proba, avail, alloc, wsA);
        prepack_b<<<dim3(SC_DIM / 128, B_DIM / 64), 256, 0, stream>>>(bsc, wsB);
        gemm_pk<<<dim3(SC_DIM / BN, S_DIM / BM), 256, 0, stream>>>(wsA, wsB, cur, out);
    } else {
        opt_gemm_fused<<<dim3(SC_DIM / BN, S_DIM / BM), 256, 0, stream>>>(
            proba, cur, bsc, avail, alloc, out);
    }
}

// Round 3
// 41.256 us; speedup vs baseline: 1.8120x; 1.0707x over previous
//
#include <hip/hip_runtime.h>

#define S_DIM  2048
#define B_DIM  1024
#define SC_DIM 4096

#define BM 128
#define BN 128
#define BK 64

typedef __bf16 bf16x8 __attribute__((ext_vector_type(8)));
typedef float  f32x4  __attribute__((ext_vector_type(4)));
typedef unsigned short u16x4 __attribute__((ext_vector_type(4)));
typedef unsigned short u16x8 __attribute__((ext_vector_type(8)));

__device__ __forceinline__ unsigned short f2bf(float f) {
    unsigned int u = __builtin_bit_cast(unsigned int, f);
    return (unsigned short)((u + 0x7FFFu + ((u >> 16) & 1u)) >> 16);
}

__device__ __forceinline__ void gld_lds16(const void* g, void* l) {
    __builtin_amdgcn_global_load_lds(
        (const __attribute__((address_space(1))) unsigned int*)g,
        (__attribute__((address_space(3))) unsigned int*)l, 16, 0, 0);
}

#define WAITCNT_VM(N) asm volatile("s_waitcnt vmcnt(" #N ")" ::: "memory")

// ---------------- prepack A: wsA[n][k] = bf16(proba*cm), 16B-chunk-swizzled ----------------
__global__ __launch_bounds__(256)
void prepack_a(const float* __restrict__ proba,
               const float* __restrict__ avail,
               const float* __restrict__ alloc,
               unsigned short* __restrict__ wsA)
{
    int c = blockIdx.x * 256 + threadIdx.x;
    int n = c >> 7;
    int G = c & 127;
    int k = G * 8;

    f32x4 p0 = *(const f32x4*)&proba[(size_t)n * B_DIM + k];
    f32x4 p1 = *(const f32x4*)&proba[(size_t)n * B_DIM + k + 4];
    f32x4 av0 = *(const f32x4*)&avail[k];
    f32x4 av1 = *(const f32x4*)&avail[k + 4];
    f32x4 al0 = *(const f32x4*)&alloc[k];
    f32x4 al1 = *(const f32x4*)&alloc[k + 4];

    u16x8 w;
    #pragma unroll
    for (int i = 0; i < 4; ++i) {
        float pv = p0[i];
        bool oa = (av0[i] - pv < 0.f) && (pv > 0.f);
        bool ob = (al0[i] + pv < 0.f) && (pv < 0.f);
        w[i] = f2bf(pv * ((oa || ob) ? 0.01f : 1.0f));
    }
    #pragma unroll
    for (int i = 0; i < 4; ++i) {
        float pv = p1[i];
        bool oa = (av1[i] - pv < 0.f) && (pv > 0.f);
        bool ob = (al1[i] + pv < 0.f) && (pv < 0.f);
        w[4 + i] = f2bf(pv * ((oa || ob) ? 0.01f : 1.0f));
    }
    int Gs = (G & ~7) | ((G & 7) ^ (n & 7));
    *(u16x8*)&wsA[(size_t)n * B_DIM + Gs * 8] = w;
}

// ---------------- prepack B: wsB[n][k] = bf16(bsc[k][n]) transposed, swizzled ----------------
__global__ __launch_bounds__(256)
void prepack_b(const float* __restrict__ bsc,
               unsigned short* __restrict__ wsB)
{
    __shared__ float lds[64][129];
    const int t = threadIdx.x;
    const int bn0 = blockIdx.x * 128;
    const int k0  = blockIdx.y * 64;

    #pragma unroll
    for (int p = 0; p < 8; ++p) {
        int kl = (t >> 5) + p * 8;
        int cl = (t & 31) * 4;
        f32x4 v = *(const f32x4*)&bsc[(size_t)(k0 + kl) * SC_DIM + bn0 + cl];
        lds[kl][cl]     = v[0];
        lds[kl][cl + 1] = v[1];
        lds[kl][cl + 2] = v[2];
        lds[kl][cl + 3] = v[3];
    }
    __syncthreads();

    #pragma unroll
    for (int p = 0; p < 4; ++p) {
        int g = t & 7;
        int n = (t >> 3) + p * 32;
        u16x8 w;
        #pragma unroll
        for (int i = 0; i < 8; ++i)
            w[i] = f2bf(lds[g * 8 + i][n]);
        int gs = g ^ (n & 7);
        *(u16x8*)&wsB[(size_t)(bn0 + n) * B_DIM + k0 + gs * 8] = w;
    }
}

// ---------------- main GEMM: double-buffered, counted-vmcnt pipeline ----------------
__global__ __launch_bounds__(256, 2)
void gemm_pk(const unsigned short* __restrict__ wsA,
             const unsigned short* __restrict__ wsB,
             const float* __restrict__ cur,
             float* __restrict__ out)
{
    __shared__ __align__(16) unsigned short sA[2][BM * BK];   // 2 x 16KB
    __shared__ __align__(16) unsigned short sB[2][BN * BK];   // 2 x 16KB

    const int tid  = threadIdx.x;
    const int lane = tid & 63;
    const int wid  = tid >> 6;
    const int wm   = wid >> 1;
    const int wn   = wid & 1;
    const int l16  = lane & 15;
    const int lg   = lane >> 4;

    // bijective XCD swizzle (512 blocks, 512 % 8 == 0)
    const int bid  = blockIdx.y * gridDim.x + blockIdx.x;
    const int swz  = (bid & 7) * 64 + (bid >> 3);
    const int bm0  = (swz >> 5) * BM;     // 16 m-tiles
    const int bn0  = (swz & 31) * BN;     // 32 n-tiles

    const int cn = tid >> 3;
    const int cg = tid & 7;

    f32x4 acc[4][4];
    #pragma unroll
    for (int i = 0; i < 4; ++i)
        #pragma unroll
        for (int j = 0; j < 4; ++j)
            acc[i][j] = {0.f, 0.f, 0.f, 0.f};

    auto stage = [&](int buf, int k0) {
        #pragma unroll
        for (int is = 0; is < 4; ++is)
            gld_lds16(wsA + (size_t)(bm0 + cn + is * 32) * B_DIM + k0 + cg * 8,
                      &sA[buf][(is * 256 + tid) * 8]);
        #pragma unroll
        for (int is = 0; is < 4; ++is)
            gld_lds16(wsB + (size_t)(bn0 + cn + is * 32) * B_DIM + k0 + cg * 8,
                      &sB[buf][(is * 256 + tid) * 8]);
    };

    auto compute = [&](int buf) {
        #pragma unroll
        for (int kk = 0; kk < 2; ++kk) {
            bf16x8 afr[4], bfr[4];
            #pragma unroll
            for (int mf = 0; mf < 4; ++mf) {
                int r = wm * 64 + mf * 16 + l16;
                afr[mf] = *(const bf16x8*)&sA[buf][r * BK + (((kk * 4 + lg) ^ (r & 7)) * 8)];
            }
            #pragma unroll
            for (int nf = 0; nf < 4; ++nf) {
                int r = wn * 64 + nf * 16 + l16;
                bfr[nf] = *(const bf16x8*)&sB[buf][r * BK + (((kk * 4 + lg) ^ (r & 7)) * 8)];
            }
            __builtin_amdgcn_s_setprio(1);
            #pragma unroll
            for (int mf = 0; mf < 4; ++mf)
                #pragma unroll
                for (int nf = 0; nf < 4; ++nf)
                    acc[mf][nf] = __builtin_amdgcn_mfma_f32_16x16x32_bf16(
                        afr[mf], bfr[nf], acc[mf][nf], 0, 0, 0);
            __builtin_amdgcn_s_setprio(0);
        }
    };

    const int NT = B_DIM / BK;   // 16
    stage(0, 0);

    #pragma unroll 2
    for (int t = 0; t < NT - 1; ++t) {
        const int buf = t & 1;
        stage(buf ^ 1, (t + 1) * BK);     // next tile: 8 loads stay in flight
        WAITCNT_VM(8);                     // wait only for CURRENT tile's 8 loads
        __builtin_amdgcn_s_barrier();
        __builtin_amdgcn_sched_barrier(0);
        compute(buf);
        __builtin_amdgcn_sched_barrier(0);
        __builtin_amdgcn_s_barrier();
    }

    // final tile: drain, then prefetch cur under the last MFMA cluster
    WAITCNT_VM(0);
    __builtin_amdgcn_s_barrier();
    __builtin_amdgcn_sched_barrier(0);

    float cpref[4][4][4];
    #pragma unroll
    for (int mf = 0; mf < 4; ++mf)
        #pragma unroll
        for (int j = 0; j < 4; ++j)
            #pragma unroll
            for (int nf = 0; nf < 4; ++nf) {
                int row = bm0 + wm * 64 + mf * 16 + lg * 4 + j;
                int col = bn0 + wn * 64 + nf * 16 + l16;
                cpref[mf][j][nf] = cur[(size_t)row * SC_DIM + col];
            }

    compute((NT - 1) & 1);

    #pragma unroll
    for (int mf = 0; mf < 4; ++mf)
        #pragma unroll
        for (int j = 0; j < 4; ++j)
            #pragma unroll
            for (int nf = 0; nf < 4; ++nf) {
                int row = bm0 + wm * 64 + mf * 16 + lg * 4 + j;
                int col = bn0 + wn * 64 + nf * 16 + l16;
                out[(size_t)row * SC_DIM + col] = cpref[mf][j][nf] + acc[mf][nf][j];
            }
}

// ---------------- fallback (fused single-pass), used only if ws too small ----------------
#define LDK 72
__global__ __launch_bounds__(256, 2)
void opt_gemm_fused(const float* __restrict__ proba,
                    const float* __restrict__ cur,
                    const float* __restrict__ bsc,
                    const float* __restrict__ avail,
                    const float* __restrict__ alloc,
                    float* __restrict__ out)
{
    __shared__ __align__(16) unsigned short sA[BM * LDK];
    __shared__ __align__(16) unsigned short sB[BN * LDK];
    const int tid = threadIdx.x;
    const int lane = tid & 63;
    const int wid = tid >> 6;
    const int wm = wid >> 1, wn = wid & 1;
    const int bm0 = blockIdx.y * BM, bn0 = blockIdx.x * BN;
    const int af4 = tid & 15, ar0 = tid >> 4;
    const int bnn = tid & 127, bkh = tid >> 7;
    const int l16 = lane & 15, lg = lane >> 4;

    f32x4 acc[4][4];
    #pragma unroll
    for (int i = 0; i < 4; ++i)
        #pragma unroll
        for (int j = 0; j < 4; ++j) acc[i][j] = {0.f, 0.f, 0.f, 0.f};

    for (int k0 = 0; k0 < B_DIM; k0 += BK) {
        f32x4 av = *(const f32x4*)&avail[k0 + af4 * 4];
        f32x4 al = *(const f32x4*)&alloc[k0 + af4 * 4];
        #pragma unroll
        for (int pass = 0; pass < 8; ++pass) {
            int r = ar0 + pass * 16;
            f32x4 p = *(const f32x4*)&proba[(size_t)(bm0 + r) * B_DIM + k0 + af4 * 4];
            u16x4 w;
            #pragma unroll
            for (int i = 0; i < 4; ++i) {
                float pv = p[i];
                bool oa = (av[i] - pv < 0.f) && (pv > 0.f);
                bool ob = (al[i] + pv < 0.f) && (pv < 0.f);
                w[i] = f2bf(pv * ((oa || ob) ? 0.01f : 1.0f));
            }
            *(u16x4*)&sA[r * LDK + af4 * 4] = w;
        }
        #pragma unroll
        for (int g = 0; g < 4; ++g) {
            u16x8 w;
            #pragma unroll
            for (int i = 0; i < 8; ++i) {
                int kk = bkh * 32 + g * 8 + i;
                w[i] = f2bf(bsc[(size_t)(k0 + kk) * SC_DIM + bn0 + bnn]);
            }
            *(u16x8*)&sB[bnn * LDK + bkh * 32 + g * 8] = w;
        }
        __syncthreads();
        #pragma unroll
        for (int kk = 0; kk < 2; ++kk) {
            bf16x8 afr[4], bfr[4];
            #pragma unroll
            for (int mf = 0; mf < 4; ++mf)
                afr[mf] = *(const bf16x8*)&sA[(wm * 64 + mf * 16 + l16) * LDK + kk * 32 + lg * 8];
            #pragma unroll
            for (int nf = 0; nf < 4; ++nf)
                bfr[nf] = *(const bf16x8*)&sB[(wn * 64 + nf * 16 + l16) * LDK + kk * 32 + lg * 8];
            #pragma unroll
            for (int mf = 0; mf < 4; ++mf)
                #pragma unroll
                for (int nf = 0; nf < 4; ++nf)
                    acc[mf][nf] = __builtin_amdgcn_mfma_f32_16x16x32_bf16(
                        afr[mf], bfr[nf], acc[mf][nf], 0, 0, 0);
        }
        __syncthreads();
    }
    #pragma unroll
    for (int mf = 0; mf < 4; ++mf)
        #pragma unroll
        for (int j = 0; j < 4; ++j) {
            int row = bm0 + wm * 64 + mf * 16 + lg * 4 + j;
            #pragma unroll
            for (int nf = 0; nf < 4; ++nf) {
                int col = bn0 + wn * 64 + nf * 16 + l16;
                size_t idx = (size_t)row * SC_DIM + col;
                out[idx] = cur[idx] + acc[mf][nf][j];
            }
        }
}

extern "C" void kernel_launch(void* const* d_in, const int* in_sizes, int n_in,
                              void* d_out, int out_size, void* d_ws, size_t ws_size,
                              hipStream_t stream) {
    const float* proba = (const float*)d_in[0];
    const float* cur   = (const float*)d_in[1];
    const float* bsc   = (const float*)d_in[2];
    const float* avail = (const float*)d_in[3];
    const float* alloc = (const float*)d_in[4];
    float* out = (float*)d_out;

    const size_t wsA_bytes = (size_t)S_DIM * B_DIM * 2;   // 4 MB
    const size_t wsB_bytes = (size_t)SC_DIM * B_DIM * 2;  // 8 MB

    if (ws_size >= wsA_bytes + wsB_bytes) {
        unsigned short* wsA = (unsigned short*)d_ws;
        unsigned short* wsB = (unsigned short*)((char*)d_ws + wsA_bytes);

        prepack_a<<<dim3(S_DIM * B_DIM / 8 / 256), 256, 0, stream>>>(proba, avail, alloc, wsA);
        prepack_b<<<dim3(SC_DIM / 128, B_DIM / 64), 256, 0, stream>>>(bsc, wsB);
        gemm_pk<<<dim3(SC_DIM / BN, S_DIM / BM), 256, 0, stream>>>(wsA, wsB, cur, out);
    } else {
        opt_gemm_fused<<<dim3(SC_DIM / BN, S_DIM / BM), 256, 0, stream>>>(
            proba, cur, bsc, avail, alloc, out);
    }
}